// Round 2
// baseline (512.008 us; speedup 1.0000x reference)
//
#include <hip/hip_runtime.h>
#include <math.h>

// DSSIM (mean), B=32 C=3 H=W=512 fp32, separable 11x11 Gaussian.
// R1: latency/occupancy fix.
//  - No raw-tile LDS: h-blur tasks load their own 24-float aligned window
//    (6x float4) straight from global; L1/L2 serve the overlap.
//  - Two-pass h/v pipeline through ONE 3-plane LDS buffer:
//      2a: h-blur(x1,x2) -> LDS   3a: v-blur -> mu1,mu2 in regs
//      2b: h-blur(x1^2,x2^2,x1x2) -> LDS (reuse)   3b: v-blur + SSIM
//    LDS 79KB -> 33KB => 4 blocks/CU (16 waves) vs 2 (8 waves).
//  - Conflict-free LDS layout: task slot 28 floats (112B), planes [xg][row];
//    b128 writes cover all 32 banks (floor), b32 reads 2 lanes/bank (free).

namespace {
constexpr int IMG = 512;
constexpr int TW = 32, TH = 64;          // output tile
constexpr int XGN = TW / 8;              // 4 col-groups of 8
constexpr int RH = TH + 10;              // 74 h-blur rows (halo 5)
constexpr int TSTR = 28;                 // floats per (xg,row) slot (pad 24->28)
constexpr int NTASK = XGN * RH;          // 296 h-tasks
constexpr int TX = IMG / TW;             // 16
constexpr int TILES = TX * (IMG / TH);   // 16*8 = 128
constexpr int NIMG = 96;                 // 32*3
constexpr float C1c = 1e-4f;
constexpr float C2c = 9e-4f;
constexpr float INV_N = 1.0f / 25165824.0f;  // 1/(96*512*512)
}

__global__ void dssim_zero(float* ws) { ws[0] = 0.0f; }

__global__ void dssim_final(const float* __restrict__ ws, float* __restrict__ out) {
  out[0] = ws[0] * INV_N;
}

__global__ __launch_bounds__(256, 4) void dssim_main(
    const float* __restrict__ im1, const float* __restrict__ im2,
    const float* __restrict__ gk, float* __restrict__ ws)
{
  __shared__ float sH[XGN * RH * TSTR];  // 33,152 B
  __shared__ float sred[4];

  const int tid = threadIdx.x;
  const int bid = blockIdx.x;
  const int img  = bid >> 7;
  const int tile = bid & 127;
  const int tx = tile & 15;
  const int ty = tile >> 4;

  const float* __restrict__ p1 = im1 + (size_t)img * (IMG * IMG);
  const float* __restrict__ p2 = im2 + (size_t)img * (IMG * IMG);

  // k1[i] = k2d[i][5] / sqrt(k2d[5][5])  (separable, sum(k1)=1)
  float wt[11];
  {
    float ic = 1.0f / sqrtf(gk[5 * 11 + 5]);
    #pragma unroll
    for (int i = 0; i < 11; ++i) wt[i] = gk[i * 11 + 5] * ic;
  }

  const int gy0 = ty * TH - 5;

  // Load 24-float raw window [X0-8, X0+16) of row (gy0+r), zero-padded.
  auto loadwin = [&](const float* __restrict__ p, int r, int X0, float* w24) {
    int gy = gy0 + r;
    if ((unsigned)gy >= (unsigned)IMG) {
      #pragma unroll
      for (int e = 0; e < 24; ++e) w24[e] = 0.f;
      return;
    }
    const float* row = p + gy * IMG;
    int cb = X0 - 8;
    if (cb >= 0 && cb + 24 <= IMG) {
      #pragma unroll
      for (int i = 0; i < 6; ++i) {
        float4 v = *(const float4*)(row + cb + 4 * i);
        w24[4 * i + 0] = v.x; w24[4 * i + 1] = v.y;
        w24[4 * i + 2] = v.z; w24[4 * i + 3] = v.w;
      }
    } else {
      #pragma unroll
      for (int e = 0; e < 24; ++e) {
        int c = cb + e;
        w24[e] = ((unsigned)c < (unsigned)IMG) ? row[c] : 0.f;
      }
    }
  };

  // ---- Phase 2a: h-blur of x1, x2 ----
  for (int t = tid; t < NTASK; t += 256) {
    int xg = t & 3, r = t >> 2;
    int X0 = tx * TW + xg * 8;
    float a24[24], b24[24];
    loadwin(p1, r, X0, a24);
    loadwin(p2, r, X0, b24);
    float o0[8], o1[8];
    #pragma unroll
    for (int j = 0; j < 8; ++j) { o0[j] = 0.f; o1[j] = 0.f; }
    #pragma unroll
    for (int e = 0; e < 18; ++e) {
      float va = a24[e + 3], vb = b24[e + 3];
      #pragma unroll
      for (int j = 0; j < 8; ++j) {
        int k = e - j;
        if (k >= 0 && k < 11) {
          o0[j] = fmaf(wt[k], va, o0[j]);
          o1[j] = fmaf(wt[k], vb, o1[j]);
        }
      }
    }
    int base = (xg * RH + r) * TSTR;
    #pragma unroll
    for (int j = 0; j < 8; ++j) sH[base + j] = o0[j];
    #pragma unroll
    for (int j = 0; j < 8; ++j) sH[base + 8 + j] = o1[j];
  }
  __syncthreads();

  // ---- Phase 3a: v-blur -> mu1, mu2 (8 rows per thread, kept in regs) ----
  const int x   = tid & 31;
  const int cl  = x & 7;
  const int xg3 = x >> 3;
  const int y0  = (tid >> 5) * 8;
  float mu1[8], mu2[8];
  #pragma unroll
  for (int j = 0; j < 8; ++j) { mu1[j] = 0.f; mu2[j] = 0.f; }
  #pragma unroll
  for (int rr = 0; rr < 18; ++rr) {
    int ad = (xg3 * RH + y0 + rr) * TSTR + cl;
    float v0 = sH[ad], v1 = sH[ad + 8];
    #pragma unroll
    for (int j = 0; j < 8; ++j) {
      int k = rr - j;
      if (k >= 0 && k < 11) {
        mu1[j] = fmaf(wt[k], v0, mu1[j]);
        mu2[j] = fmaf(wt[k], v1, mu2[j]);
      }
    }
  }
  __syncthreads();

  // ---- Phase 2b: h-blur of x1^2, x2^2, x1*x2 (reuse sH) ----
  for (int t = tid; t < NTASK; t += 256) {
    int xg = t & 3, r = t >> 2;
    int X0 = tx * TW + xg * 8;
    float a24[24], b24[24];
    loadwin(p1, r, X0, a24);
    loadwin(p2, r, X0, b24);
    float q0[8], q1[8], q2[8];
    #pragma unroll
    for (int j = 0; j < 8; ++j) { q0[j] = 0.f; q1[j] = 0.f; q2[j] = 0.f; }
    #pragma unroll
    for (int e = 0; e < 18; ++e) {
      float va = a24[e + 3], vb = b24[e + 3];
      float pa = va * va, pb = vb * vb, pab = va * vb;
      #pragma unroll
      for (int j = 0; j < 8; ++j) {
        int k = e - j;
        if (k >= 0 && k < 11) {
          q0[j] = fmaf(wt[k], pa, q0[j]);
          q1[j] = fmaf(wt[k], pb, q1[j]);
          q2[j] = fmaf(wt[k], pab, q2[j]);
        }
      }
    }
    int base = (xg * RH + r) * TSTR;
    #pragma unroll
    for (int j = 0; j < 8; ++j) sH[base + j] = q0[j];
    #pragma unroll
    for (int j = 0; j < 8; ++j) sH[base + 8 + j] = q1[j];
    #pragma unroll
    for (int j = 0; j < 8; ++j) sH[base + 16 + j] = q2[j];
  }
  __syncthreads();

  // ---- Phase 3b: v-blur of quadratics + SSIM + reduce ----
  float e11[8], e22[8], e12[8];
  #pragma unroll
  for (int j = 0; j < 8; ++j) { e11[j] = 0.f; e22[j] = 0.f; e12[j] = 0.f; }
  #pragma unroll
  for (int rr = 0; rr < 18; ++rr) {
    int ad = (xg3 * RH + y0 + rr) * TSTR + cl;
    float v0 = sH[ad], v1 = sH[ad + 8], v2 = sH[ad + 16];
    #pragma unroll
    for (int j = 0; j < 8; ++j) {
      int k = rr - j;
      if (k >= 0 && k < 11) {
        e11[j] = fmaf(wt[k], v0, e11[j]);
        e22[j] = fmaf(wt[k], v1, e22[j]);
        e12[j] = fmaf(wt[k], v2, e12[j]);
      }
    }
  }

  float lsum = 0.f;
  #pragma unroll
  for (int j = 0; j < 8; ++j) {
    float m1 = mu1[j], m2 = mu2[j];
    float m1s = m1 * m1, m2s = m2 * m2, m12 = m1 * m2;
    float s11 = e11[j] - m1s, s22 = e22[j] - m2s, s12 = e12[j] - m12;
    float num = (2.f * m12 + C1c) * (2.f * s12 + C2c);
    float den = (m1s + m2s + C1c) * (s11 + s22 + C2c);
    lsum += (1.f - num / den) * 0.5f;
  }

  #pragma unroll
  for (int off = 32; off > 0; off >>= 1) lsum += __shfl_down(lsum, off);
  if ((tid & 63) == 0) sred[tid >> 6] = lsum;
  __syncthreads();
  if (tid == 0) atomicAdd(ws, sred[0] + sred[1] + sred[2] + sred[3]);
}

extern "C" void kernel_launch(void* const* d_in, const int* in_sizes, int n_in,
                              void* d_out, int out_size, void* d_ws, size_t ws_size,
                              hipStream_t stream) {
  const float* im1 = (const float*)d_in[0];
  const float* im2 = (const float*)d_in[1];
  const float* gk  = (const float*)d_in[2];
  float* out = (float*)d_out;
  float* ws  = (float*)d_ws;

  hipLaunchKernelGGL(dssim_zero, dim3(1), dim3(1), 0, stream, ws);
  hipLaunchKernelGGL(dssim_main, dim3(NIMG * TILES), dim3(256), 0, stream,
                     im1, im2, gk, ws);
  hipLaunchKernelGGL(dssim_final, dim3(1), dim3(1), 0, stream, ws, out);
}

// Round 3
// 302.870 us; speedup vs baseline: 1.6905x; 1.6905x over previous
//
#include <hip/hip_runtime.h>
#include <math.h>

// DSSIM (mean), B=32 C=3 H=W=512 fp32, separable 11x11 Gaussian.
// R2: h-first sliding-ring structure.
//  - Block = 32-col strip of one image, sweeps 512 rows in 8 chunks of 64.
//  - h-phase: 256 tasks/chunk load their own aligned 24-float raw windows
//    from global (each raw row read ONCE per strip), compute 5 h-planes,
//    write 4+1-packed (b128) into a 74-row LDS ring.
//  - v-phase: per tap row read b128 (planes 0-3) + b32 (plane 4); ring
//    carries the 10-row v-halo across chunks => no h-blur recompute.
//  - LDS 52.1 KB -> 3 blocks/CU; bank-group-uniform layout (slot stride 44).

namespace {
constexpr int IMG = 512;
constexpr int TW = 32;                 // strip width (output cols)
constexpr int RB = 64;                 // output rows per chunk
constexpr int RING = RB + 10;          // 74 ring rows
constexpr int SLOT = 44;               // floats per (xg, ringrow) slot
constexpr int XGN = TW / 8;            // 4 col-groups
constexpr int NCHUNK = IMG / RB;       // 8
constexpr int CTILES = IMG / TW;       // 16 strips per image
constexpr int NIMG = 96;               // 32*3
constexpr float C1c = 1e-4f;
constexpr float C2c = 9e-4f;
constexpr float INV_N = 1.0f / 25165824.0f;  // 1/(96*512*512)
}

__global__ void dssim_zero(float* ws) { ws[0] = 0.0f; }

__global__ void dssim_final(const float* __restrict__ ws, float* __restrict__ out) {
  out[0] = ws[0] * INV_N;
}

__global__ __launch_bounds__(256, 3) void dssim_main(
    const float* __restrict__ im1, const float* __restrict__ im2,
    const float* __restrict__ gk, float* __restrict__ ws)
{
  __shared__ float sR[XGN * RING * SLOT];   // 52,096 B

  const int tid = threadIdx.x;
  const int bid = blockIdx.x;
  const int img = bid >> 4;               // 16 strips per image
  const int tsx = bid & 15;
  const int X0s = tsx * TW;

  const float* __restrict__ p1 = im1 + (size_t)img * (IMG * IMG);
  const float* __restrict__ p2 = im2 + (size_t)img * (IMG * IMG);

  // k1[i] = k2d[i][5] / sqrt(k2d[5][5])
  float wt[11];
  {
    float ic = 1.0f / sqrtf(gk[5 * 11 + 5]);
    #pragma unroll
    for (int i = 0; i < 11; ++i) wt[i] = gk[i * 11 + 5] * ic;
  }

  // v-phase thread mapping (fixed across chunks)
  const int c   = tid & 31;               // column within strip
  const int yg  = tid >> 5;               // 0..7 row-group of 8
  const int xg3 = c >> 3;
  const int cl  = c & 7;

  float lsum = 0.f;

  for (int k = 0; k < NCHUNK; ++k) {
    // ---- h-phase: produce new h-rows into the ring ----
    const int r0    = (k == 0) ? -5 : RB * k + 5;
    const int ntask = (k == 0) ? XGN * RING : XGN * RB;
    for (int t = tid; t < ntask; t += 256) {
      const int xg = t & 3, dr = t >> 2;
      const int r  = r0 + dr;
      const int rr = (r + 5) % RING;      // ring slot row
      const int X0 = X0s + xg * 8;
      const int cb = X0 - 8;

      float a24[24], b24[24];
      if ((unsigned)r < (unsigned)IMG) {
        const float* row1 = p1 + r * IMG;
        const float* row2 = p2 + r * IMG;
        if (cb >= 0 && cb + 24 <= IMG) {
          #pragma unroll
          for (int i = 0; i < 6; ++i) {
            float4 v1 = *(const float4*)(row1 + cb + 4 * i);
            float4 v2 = *(const float4*)(row2 + cb + 4 * i);
            a24[4*i+0] = v1.x; a24[4*i+1] = v1.y; a24[4*i+2] = v1.z; a24[4*i+3] = v1.w;
            b24[4*i+0] = v2.x; b24[4*i+1] = v2.y; b24[4*i+2] = v2.z; b24[4*i+3] = v2.w;
          }
        } else {
          #pragma unroll
          for (int e = 0; e < 24; ++e) {
            int cc = cb + e;
            bool ok = (unsigned)cc < (unsigned)IMG;
            a24[e] = ok ? row1[cc] : 0.f;
            b24[e] = ok ? row2[cc] : 0.f;
          }
        }
      } else {
        #pragma unroll
        for (int e = 0; e < 24; ++e) { a24[e] = 0.f; b24[e] = 0.f; }
      }

      float o0[8], o1[8], o2[8], o3[8], o4[8];
      #pragma unroll
      for (int j = 0; j < 8; ++j) { o0[j]=0.f; o1[j]=0.f; o2[j]=0.f; o3[j]=0.f; o4[j]=0.f; }
      #pragma unroll
      for (int e = 0; e < 18; ++e) {
        float va = a24[e + 3], vb = b24[e + 3];
        float pa = va * va, pb = vb * vb, pab = va * vb;
        #pragma unroll
        for (int j = 0; j < 8; ++j) {
          int kk = e - j;
          if (kk >= 0 && kk < 11) {
            float w = wt[kk];
            o0[j] = fmaf(w, va,  o0[j]);
            o1[j] = fmaf(w, vb,  o1[j]);
            o2[j] = fmaf(w, pa,  o2[j]);
            o3[j] = fmaf(w, pb,  o3[j]);
            o4[j] = fmaf(w, pab, o4[j]);
          }
        }
      }

      const int base = (xg * RING + rr) * SLOT;
      #pragma unroll
      for (int j = 0; j < 8; ++j)
        *(float4*)&sR[base + 4 * j] = make_float4(o0[j], o1[j], o2[j], o3[j]);
      *(float4*)&sR[base + 32] = make_float4(o4[0], o4[1], o4[2], o4[3]);
      *(float4*)&sR[base + 36] = make_float4(o4[4], o4[5], o4[6], o4[7]);
    }
    __syncthreads();

    // ---- v-phase: 8 output rows per thread + SSIM ----
    float mu1[8], mu2[8], e11[8], e22[8], e12[8];
    #pragma unroll
    for (int j = 0; j < 8; ++j) { mu1[j]=0.f; mu2[j]=0.f; e11[j]=0.f; e22[j]=0.f; e12[j]=0.f; }

    const int rbase = (RB * k + yg * 8) % RING;
    #pragma unroll
    for (int rrr = 0; rrr < 18; ++rrr) {
      int idx = rbase + rrr;
      if (idx >= RING) idx -= RING;
      const int a = (xg3 * RING + idx) * SLOT;
      float4 v4 = *(const float4*)&sR[a + 4 * cl];
      float  v5 = sR[a + 32 + cl];
      #pragma unroll
      for (int j = 0; j < 8; ++j) {
        int kk = rrr - j;
        if (kk >= 0 && kk < 11) {
          float w = wt[kk];
          mu1[j] = fmaf(w, v4.x, mu1[j]);
          mu2[j] = fmaf(w, v4.y, mu2[j]);
          e11[j] = fmaf(w, v4.z, e11[j]);
          e22[j] = fmaf(w, v4.w, e22[j]);
          e12[j] = fmaf(w, v5,  e12[j]);
        }
      }
    }

    #pragma unroll
    for (int j = 0; j < 8; ++j) {
      float m1 = mu1[j], m2 = mu2[j];
      float m1s = m1 * m1, m2s = m2 * m2, m12 = m1 * m2;
      float s11 = e11[j] - m1s, s22 = e22[j] - m2s, s12 = e12[j] - m12;
      float num = (2.f * m12 + C1c) * (2.f * s12 + C2c);
      float den = (m1s + m2s + C1c) * (s11 + s22 + C2c);
      lsum += (1.f - num / den) * 0.5f;
    }
    __syncthreads();   // protect ring rows still needed? (next h overwrites read rows)
  }

  // wave-level reduce, one atomic per wave (4/block)
  #pragma unroll
  for (int off = 32; off > 0; off >>= 1) lsum += __shfl_down(lsum, off);
  if ((tid & 63) == 0) atomicAdd(ws, lsum);
}

extern "C" void kernel_launch(void* const* d_in, const int* in_sizes, int n_in,
                              void* d_out, int out_size, void* d_ws, size_t ws_size,
                              hipStream_t stream) {
  const float* im1 = (const float*)d_in[0];
  const float* im2 = (const float*)d_in[1];
  const float* gk  = (const float*)d_in[2];
  float* out = (float*)d_out;
  float* ws  = (float*)d_ws;

  hipLaunchKernelGGL(dssim_zero, dim3(1), dim3(1), 0, stream, ws);
  hipLaunchKernelGGL(dssim_main, dim3(NIMG * CTILES), dim3(256), 0, stream,
                     im1, im2, gk, ws);
  hipLaunchKernelGGL(dssim_final, dim3(1), dim3(1), 0, stream, ws, out);
}